// Round 18
// baseline (6524.903 us; speedup 1.0000x reference)
//
#include <hip/hip_runtime.h>
#include <hip/hip_fp16.h>

// LP=500, LQ=64, B=64, D=256, H=150
#define LP 500

typedef _Float16 h2f __attribute__((ext_vector_type(2)));
typedef _Float16 h8f __attribute__((ext_vector_type(8)));

// ---------------- workspace layout (float slots) ----------------
constexpr size_t OFF_WVH2 = 0;         // [76][608] h2f: cols 0..149 Wv rows, 150..599 Whh rows, pads 0
constexpr size_t OFF_WGF2 = 46208;     // [128][512] h2f folded Wg cc-part
constexpr size_t OFF_WIH2 = 111744;    // [256][452] h2f Wih (cols 450,451 zero)
constexpr size_t OFF_WPF  = 227456;    // [150][256] f32 folded Wp
constexpr size_t OFF_WQF  = 265856;    // [150][256] f32 folded Wq
constexpr size_t OFF_WUQ  = 304256;    // [64][64][150] f32 Wuq[q][b][h]
constexpr size_t OFF_P1   = 918656;    // [500][64][150] f32  (WG1 [512][256] f32 ALIASED here pre-P1)
constexpr size_t OFF_WG1  = OFF_P1;    // alias: consumed by Gu GEMM before P1 GEMM overwrites
constexpr size_t OFF_GUH  = 5718656;   // [500][64][512] f16 Gu
constexpr size_t OFF_UPT  = 13910656;  // [500][256][64] f32 (M2 [64][32][512] h2f ALIASED post-GEMMs)
constexpr size_t OFF_M2   = OFF_UPT;   // alias: UPT dead after the three k_gemm calls
constexpr size_t OFF_UQT  = 22102656;  // [64][256][64] f32   (UqT2 [64][32][256] h2f ALIASED post-GEMM)
constexpr size_t OFF_UQT2 = OFF_UQT;
constexpr size_t WS_FLOATS = 23151232; // 92.6 MB

// ---------------- helpers ----------------
__device__ __forceinline__ float fast_rcp(float x) { return __builtin_amdgcn_rcpf(x); }
__device__ __forceinline__ float sigm(float x)   { return fast_rcp(1.f + __expf(-x)); }
__device__ __forceinline__ float tanh_f(float x) { return 1.f - 2.f * fast_rcp(1.f + __expf(2.f * x)); }

// ---------------- precompute: weight folds + f16 column-major packs ----------------
__global__ __launch_bounds__(256) void k_prep(const float* __restrict__ Wp, const float* __restrict__ Wq,
                                              const float* __restrict__ Wg, const float* __restrict__ Wv,
                                              const float* __restrict__ Whh, const float* __restrict__ Wih,
                                              float* __restrict__ ws) {
    int i = blockIdx.x * 256 + threadIdx.x;
    if (i < 46208) {  // WVH2 [76][608]
        int k2 = i / 608, m = i - k2 * 608;
        float lo = 0.f, hi = 0.f;
        if (k2 < 75 && m < 600) {
            if (m < 150) { lo = Wv[m * 150 + 2 * k2]; hi = Wv[m * 150 + 2 * k2 + 1]; }
            else { int mm = m - 150; lo = Whh[mm * 150 + 2 * k2]; hi = Whh[mm * 150 + 2 * k2 + 1]; }
        }
        ((h2f*)(ws + OFF_WVH2))[i] = h2f{(_Float16)lo, (_Float16)hi};
        return;
    }
    i -= 46208;
    if (i < 65536) {  // WGF2 [128][512]
        int k2 = i >> 9, j = i & 511;
        int d = 2 * k2;
        size_t r = (size_t)(512 + j) * 1024;
        float lo = Wg[r + 512 + d] + Wg[r + 768 + d];
        float hi = Wg[r + 512 + d + 1] + Wg[r + 768 + d + 1];
        ((h2f*)(ws + OFF_WGF2))[i] = h2f{(_Float16)lo, (_Float16)hi};
        return;
    }
    i -= 65536;
    if (i < 115712) {  // WIH2 [256][452]
        int k2 = i / 452, m = i - k2 * 452;
        float lo = 0.f, hi = 0.f;
        if (m < 450) { lo = Wih[m * 512 + 2 * k2]; hi = Wih[m * 512 + 2 * k2 + 1]; }
        ((h2f*)(ws + OFF_WIH2))[i] = h2f{(_Float16)lo, (_Float16)hi};
        return;
    }
    i -= 115712;
    if (i < 38400) { int h = i >> 8, d = i & 255; ws[OFF_WPF + i] = Wp[h * 512 + d] + Wp[h * 512 + 256 + d]; return; }
    i -= 38400;
    if (i < 38400) { int h = i >> 8, d = i & 255; ws[OFF_WQF + i] = Wq[h * 512 + d] + Wq[h * 512 + 256 + d]; return; }
    i -= 38400;
    if (i < 131072) { int j = i >> 8, d = i & 255; size_t r = (size_t)(512 + j) * 1024; ws[OFF_WG1 + i] = Wg[r + d] + Wg[r + 256 + d]; return; }
}

// transpose X[t][64][256] -> XT[t][256][64], one block per t
__global__ __launch_bounds__(256) void k_tr(const float* __restrict__ X, float* __restrict__ XT) {
    __shared__ float tile[64][65];
    size_t base = (size_t)blockIdx.x * 16384;
    for (int ph = 0; ph < 4; ++ph) {
        for (int i = threadIdx.x; i < 4096; i += 256) {
            int b = i >> 6, dl = i & 63;
            tile[b][dl] = X[base + (size_t)b * 256 + ph * 64 + dl];
        }
        __syncthreads();
        for (int i = threadIdx.x; i < 4096; i += 256) {
            int d = i >> 6, bl = i & 63;
            XT[base + (size_t)(ph * 64 + d) * 64 + bl] = tile[bl][d];
        }
        __syncthreads();
    }
}

// acc[h,b] = sum_d XT[t,d,b]*Wf[h,d]; writes out[t][b][Hrows] as f32 or f16
__global__ __launch_bounds__(256) void k_gemm(const float* __restrict__ XT, const float* __restrict__ Wf,
                                              float* __restrict__ outF, _Float16* __restrict__ outH,
                                              int Hrows, int tilesPerT) {
    __shared__ float OL[64 * 33];
    int bidx = blockIdx.x;
    int t = bidx / tilesPerT, tile = bidx - t * tilesPerT;
    int w = threadIdx.x >> 6, lane = threadIdx.x & 63;
    int h0 = __builtin_amdgcn_readfirstlane(tile * 32 + w * 8);
    const float* x = XT + (size_t)t * 16384;
    float acc[8];
    const float* wr[8];
#pragma unroll
    for (int r = 0; r < 8; ++r) {
        int hr = h0 + r; if (hr >= Hrows) hr = Hrows - 1;
        wr[r] = Wf + (size_t)hr * 256;
        acc[r] = 0.f;
    }
    for (int d = 0; d < 256; d += 4) {
        float cv0 = x[(d + 0) * 64 + lane];
        float cv1 = x[(d + 1) * 64 + lane];
        float cv2 = x[(d + 2) * 64 + lane];
        float cv3 = x[(d + 3) * 64 + lane];
#pragma unroll
        for (int r = 0; r < 8; ++r) {
            float4 wv = *(const float4*)(wr[r] + d);
            acc[r] += cv0 * wv.x + cv1 * wv.y + cv2 * wv.z + cv3 * wv.w;
        }
    }
#pragma unroll
    for (int r = 0; r < 8; ++r) { int hl = w * 8 + r; OL[lane * 33 + hl] = acc[r]; }
    __syncthreads();
    int hbase = tile * 32;
    int nh = Hrows - hbase; if (nh > 32) nh = 32;
    for (int i = threadIdx.x; i < 64 * nh; i += 256) {
        int b = i / nh, hl = i - b * nh;
        float val = OL[b * 33 + hl];
        size_t idx = (size_t)t * 64 * Hrows + (size_t)b * Hrows + hbase + hl;
        if (outF) outF[idx] = val;
        else outH[idx] = (_Float16)val;
    }
}

// UqT2[b][q2][d] = (f16 Uq[2q2][b][d], f16 Uq[2q2+1][b][d])
__global__ __launch_bounds__(256) void k_uqt(const float* __restrict__ Uq, h2f* __restrict__ UqT2) {
    int b = blockIdx.x, d = threadIdx.x;
    for (int q2 = 0; q2 < 32; ++q2) {
        float lo = Uq[(size_t)(2 * q2) * 16384 + b * 256 + d];
        float hi = Uq[(size_t)(2 * q2 + 1) * 16384 + b * 256 + d];
        UqT2[(size_t)b * 8192 + q2 * 256 + d] = h2f{(_Float16)lo, (_Float16)hi};
    }
}

// M[b][q][j] = sum_d f16(Uq[q][b][d]) * Wgf2[d][j]; stored as q-pairs M2[b][q2][j] h2f.
// NOTE: no __restrict__ on ws_ro/M2 (both derive from ws — avoid aliasing-UB risk).
__global__ __launch_bounds__(512) void k_mgemm(const float* __restrict__ Uq,
                                               const float* ws_ro,
                                               h2f* M2) {
    __shared__ _Float16 uqf[64 * 256];  // 32KB, f16-rounded Uq rows (matches uql quantization)
    int b = blockIdx.x, j = threadIdx.x;
    const h2f* Wgf2 = (const h2f*)(ws_ro + OFF_WGF2);
    for (int u = threadIdx.x; u < 16384; u += 512) {
        int q = u >> 8, d = u & 255;
        uqf[u] = (_Float16)Uq[(size_t)q * 16384 + b * 256 + d];
    }
    __syncthreads();
    for (int qc = 0; qc < 8; ++qc) {
        float acc[8];
#pragma unroll
        for (int i = 0; i < 8; ++i) acc[i] = 0.f;
        for (int k2 = 0; k2 < 128; ++k2) {
            h2f w = Wgf2[k2 * 512 + j];
            float wlo = (float)w[0], whi = (float)w[1];
#pragma unroll
            for (int i = 0; i < 8; ++i) {
                acc[i] += (float)uqf[(qc * 8 + i) * 256 + 2 * k2] * wlo
                        + (float)uqf[(qc * 8 + i) * 256 + 2 * k2 + 1] * whi;
            }
        }
#pragma unroll
        for (int p = 0; p < 4; ++p)
            M2[(size_t)b * 16384 + (size_t)(qc * 4 + p) * 512 + j] =
                h2f{(_Float16)acc[2 * p], (_Float16)acc[2 * p + 1]};
    }
}

// ---------------- per-batch persistent scan: 64 blocks x 768 threads ----------------
// v17 = v16 (verified ~5095 µs) + phase-concurrency restructure of phase1:
//  - phase1-pb: ONLY pb columns (quads 0..37, cols 0..151), 20-way k-split, 760 thr.
//    Exposed stream 182 -> 46 KB/step. Quad 37 spans cols 148..151, so the pb-reduce
//    also produces ghf[0..1].
//  - gh-GEMV (cols 152..599 = 112 quads, 136 KB stream) runs on waves 8..11
//    CONCURRENTLY with phase2a's tanh on waves 0..7 (8 q/wave, wq[24]) — m114-style
//    load-wave/VALU-wave overlap hides gh's stream. Partials -> red[2048..2943],
//    reduced into ghf[2..449] by threads 64..511 during the softmax phase.
//  Same 8 barriers as v16. Regrouped sums (pb 20-way, gh 2-way) perturb ~1e-6.
//  Spill check: wq 18->24 f16 (+3 regs). WRITE_SIZE must stay ~19500 KB.
__global__ __launch_bounds__(768, 3) void k_scan17(
    const float* __restrict__ V, const float* __restrict__ v0,
    const float* __restrict__ bih, const float* __restrict__ bhh,
    const float* __restrict__ ws, float* __restrict__ out) {
    __shared__ __attribute__((aligned(16))) float red[3072];
    __shared__ __attribute__((aligned(16))) _Float16 vh[152];
    __shared__ float pbf[152];
    __shared__ float ghf[452];
    __shared__ float Vb[152];
    __shared__ float bihL[452];
    __shared__ float bhhL[452];
    __shared__ float vf[152];
    __shared__ float sa[64];
    __shared__ __attribute__((aligned(8))) h2f sah[32];
    __shared__ __attribute__((aligned(8))) h2f c_p[256];
    __shared__ __attribute__((aligned(16))) h2f uql[8192];      // 32KB Uq f16 q-pairs
    __shared__ __attribute__((aligned(16))) h2f m2l[16384];     // 64KB M q-pairs
    __shared__ __attribute__((aligned(16))) h2f wihl[18 * 452]; // 32.5KB Wih2 rows ks*44+i, i<3

    const int tid = threadIdx.x, b = blockIdx.x;
    const int lane = tid & 63;
    const h2f* Wvh2 = (const h2f*)(ws + OFF_WVH2);
    const h2f* Wih2 = (const h2f*)(ws + OFF_WIH2);
    const h2f* UqT2b = (const h2f*)(ws + OFF_UQT2) + (size_t)b * 8192;
    const h2f* M2b = (const h2f*)(ws + OFF_M2) + (size_t)b * 16384;
    const float* WuqG = ws + OFF_WUQ;
    const float* P1 = ws + OFF_P1;
    const _Float16* GuH = (const _Float16*)(ws + OFF_GUH);

    // phase1-pb: 38 quads (cols 0..151) x 20 k-groups (760 threads)
    const int pA_g = tid / 38, pA_mq = tid - pA_g * 38;
    const int pA_cnt = (pA_g < 16) ? 4 : 3;
    const int pA_r0 = (pA_g < 16) ? pA_g * 4 : 64 + (pA_g - 16) * 3;
    const h2f* pbw_base = Wvh2 + (size_t)pA_r0 * 608 + 4 * pA_mq;
    // phase4: M=452(450 live), 113 quads x ks=6 (678 threads), 44 rows each
    const int p4_ks = tid / 113, p4_mq = tid - p4_ks * 113;
    const h2f* wih_base = Wih2 + (size_t)(p4_ks * 44) * 452 + 4 * p4_mq;

    // phase2a setup: waves 0..7 handle 8 q each; Wuq in regs (24 f16 = 12 regs)
    const int w12 = tid >> 6;
    _Float16 wq[24];
#pragma unroll
    for (int i = 0; i < 8; ++i)
#pragma unroll
        for (int it = 0; it < 3; ++it) {
            int idx = lane + 64 * it;
            wq[i * 3 + it] = (_Float16)((w12 < 8 && idx < 150) ? WuqG[(size_t)(w12 * 8 + i) * 9600 + b * 150 + idx] : 0.f);
        }

    // register-resident Wih2 rows i=3..14 of each 44-row group (48 regs, AGPR-hosted)
    h8f wihr[12];
#pragma unroll
    for (int i = 0; i < 12; ++i)
        wihr[i] = (tid < 678) ? *(const h8f*)(wih_base + (size_t)(3 + i) * 452) : h8f{};

    // one-time LDS residency fills (h8f vector copies)
    {
        const h8f* su = (const h8f*)UqT2b;
        h8f* du = (h8f*)uql;
        for (int u = tid; u < 2048; u += 768) du[u] = su[u];
        const h8f* sm = (const h8f*)M2b;
        h8f* dm = (h8f*)m2l;
        for (int u = tid; u < 4096; u += 768) dm[u] = sm[u];
        h8f* dw = (h8f*)wihl;
        for (int u = tid; u < 2034; u += 768) {       // 18 rows x 113 h8f
            int slot = u / 113, off = u - slot * 113; // slot = ks*3+i
            int ks = slot / 3, i = slot - ks * 3;
            dw[u] = *(const h8f*)(Wih2 + (size_t)(ks * 44 + i) * 452 + off * 4);
        }
    }

    // one-time per-b LDS init
    for (int i = tid; i < 150; i += 768) { Vb[i] = V[b * 150 + i]; float v = v0[b * 150 + i]; vf[i] = v; vh[i] = (_Float16)v; }
    for (int i = tid; i < 450; i += 768) { bihL[i] = bih[i]; bhhL[i] = bhh[i]; }
    if (tid < 2) vh[150 + tid] = (_Float16)0.f;
    __syncthreads();

    for (int t = 0; t < LP; ++t) {
        // ---- prefetch this step's HBM/L2-resident per-step data ----
        float p1v = 0.f;
        if (tid < 150) p1v = P1[(size_t)t * 9600 + b * 150 + tid];
        float guv = 0.f;
        if (tid < 512) guv = (float)GuH[(size_t)t * 32768 + b * 512 + tid];

        // ---- phase1-pb: pb partials only (cols 0..151), 20 k-groups x <=4 rows ----
        if (tid < 760) {
            const h2f* vh2 = (const h2f*)vh;
            float a0 = 0.f, a1 = 0.f, a2 = 0.f, a3 = 0.f;
#pragma unroll
            for (int i = 0; i < 4; ++i) {
                if (i < pA_cnt) {
                    h8f w = *(const h8f*)(pbw_base + (size_t)i * 608);
                    h2f x = vh2[pA_r0 + i];
                    a0 = __builtin_amdgcn_fdot2(h2f{w[0], w[1]}, x, a0, false);
                    a1 = __builtin_amdgcn_fdot2(h2f{w[2], w[3]}, x, a1, false);
                    a2 = __builtin_amdgcn_fdot2(h2f{w[4], w[5]}, x, a2, false);
                    a3 = __builtin_amdgcn_fdot2(h2f{w[6], w[7]}, x, a3, false);
                }
            }
            *(float4*)(red + pA_g * 152 + 4 * pA_mq) = float4{a0, a1, a2, a3};
        }
        __syncthreads();
        if (tid < 152) {  // pb-reduce (20-way); cols 150,151 are gh[0],gh[1]
            float s = 0.f;
#pragma unroll
            for (int g = 0; g < 20; ++g) s += red[g * 152 + tid];
            if (tid < 150) pbf[tid] = s + p1v;
            else ghf[tid - 150] = s + bhhL[tid - 150];
        }
        __syncthreads();
        // ---- phase2a (waves 0..7: 8 q each) ∥ gh-GEMV (waves 8..11, cols 152..599) ----
        if (w12 < 8) {
#pragma unroll
            for (int i = 0; i < 8; ++i) {
                int q = w12 * 8 + i;
                float part = 0.f;
#pragma unroll
                for (int it = 0; it < 3; ++it) {
                    int idx = lane + 64 * it;
                    if (idx < 150)
                        part += tanh_f(pbf[idx] + (float)wq[i * 3 + it]) * Vb[idx];
                }
                part += __shfl_xor(part, 32); part += __shfl_xor(part, 16);
                part += __shfl_xor(part, 8);  part += __shfl_xor(part, 4);
                part += __shfl_xor(part, 2);  part += __shfl_xor(part, 1);
                if (lane == 0) sa[q] = part;
            }
        } else {
            int u = tid - 512;                 // 0..255 on waves 8..11
            if (u < 224) {
                int ks = u / 112, mq = u - ks * 112;
                const h2f* ghw = Wvh2 + (size_t)(ks * 38) * 608 + 4 * (38 + mq);
                const h2f* vh2 = (const h2f*)vh;
                float a0 = 0.f, a1 = 0.f, a2 = 0.f, a3 = 0.f;
#pragma unroll 19
                for (int r = 0; r < 38; ++r) {
                    h8f w = *(const h8f*)(ghw + (size_t)r * 608);
                    h2f x = vh2[ks * 38 + r];
                    a0 = __builtin_amdgcn_fdot2(h2f{w[0], w[1]}, x, a0, false);
                    a1 = __builtin_amdgcn_fdot2(h2f{w[2], w[3]}, x, a1, false);
                    a2 = __builtin_amdgcn_fdot2(h2f{w[4], w[5]}, x, a2, false);
                    a3 = __builtin_amdgcn_fdot2(h2f{w[6], w[7]}, x, a3, false);
                }
                *(float4*)(red + 2048 + ks * 448 + 4 * mq) = float4{a0, a1, a2, a3};
            }
        }
        __syncthreads();
        // ---- softmax (wave0) ∥ gh-reduce (threads 64..511 -> ghf[2..449]) ----
        if (tid < 64) {
            float s = sa[tid];
            float m = s;
            m = fmaxf(m, __shfl_xor(m, 32)); m = fmaxf(m, __shfl_xor(m, 16));
            m = fmaxf(m, __shfl_xor(m, 8));  m = fmaxf(m, __shfl_xor(m, 4));
            m = fmaxf(m, __shfl_xor(m, 2));  m = fmaxf(m, __shfl_xor(m, 1));
            float e = __expf(s - m);
            float su = e;
            su += __shfl_xor(su, 32); su += __shfl_xor(su, 16); su += __shfl_xor(su, 8);
            su += __shfl_xor(su, 4);  su += __shfl_xor(su, 2);  su += __shfl_xor(su, 1);
            float a = e * fast_rcp(su);
            float an = __shfl_xor(a, 1);
            if ((tid & 1) == 0) sah[tid >> 1] = h2f{(_Float16)a, (_Float16)an};
        } else if (tid < 512) {
            int u = tid - 64;  // 0..447 -> gh cols 152..599 -> ghf[2+u]
            ghf[2 + u] = red[2048 + u] + red[2048 + 448 + u] + bhhL[2 + u];
        }
        __syncthreads();
        // ---- phase2b': cc partials (256 thr) ∥ g partials from M (512 thr) ----
        if (tid < 256) {
            int cks = tid >> 6, cqd = tid & 63;
            float a0 = 0.f, a1 = 0.f, a2 = 0.f, a3 = 0.f;
#pragma unroll
            for (int i = 0; i < 8; ++i) {
                int q2 = cks * 8 + i;
                h8f u = *(const h8f*)(uql + q2 * 256 + 4 * cqd);
                h2f ap = sah[q2];
                a0 = __builtin_amdgcn_fdot2(h2f{u[0], u[1]}, ap, a0, false);
                a1 = __builtin_amdgcn_fdot2(h2f{u[2], u[3]}, ap, a1, false);
                a2 = __builtin_amdgcn_fdot2(h2f{u[4], u[5]}, ap, a2, false);
                a3 = __builtin_amdgcn_fdot2(h2f{u[6], u[7]}, ap, a3, false);
            }
            *(float4*)(red + cks * 256 + 4 * cqd) = float4{a0, a1, a2, a3};
        } else {
            int gt = tid - 256, gks = gt >> 7, gjq = gt & 127;
            float a0 = 0.f, a1 = 0.f, a2 = 0.f, a3 = 0.f;
#pragma unroll
            for (int i = 0; i < 8; ++i) {
                int q2 = gks * 8 + i;
                h8f m8 = *(const h8f*)(m2l + q2 * 512 + 4 * gjq);
                h2f ap = sah[q2];
                a0 = __builtin_amdgcn_fdot2(h2f{m8[0], m8[1]}, ap, a0, false);
                a1 = __builtin_amdgcn_fdot2(h2f{m8[2], m8[3]}, ap, a1, false);
                a2 = __builtin_amdgcn_fdot2(h2f{m8[4], m8[5]}, ap, a2, false);
                a3 = __builtin_amdgcn_fdot2(h2f{m8[6], m8[7]}, ap, a3, false);
            }
            *(float4*)(red + 1024 + gks * 512 + 4 * gjq) = float4{a0, a1, a2, a3};
        }
        __syncthreads();
        // ---- grc: g reduce + cc reduce + c_ pack (512 threads, j = tid) ----
        if (tid < 512) {
            float g = guv + red[1024 + tid] + red[1536 + tid] + red[2048 + tid] + red[2560 + tid];
            int dd = tid & 255;
            float cc = red[dd] + red[256 + dd] + red[512 + dd] + red[768 + dd];
            float val = sigm(g) * cc;
            float vn2 = __shfl_xor(val, 1);
            if ((tid & 1) == 0) c_p[tid >> 1] = h2f{(_Float16)val, (_Float16)vn2};
        }
        __syncthreads();
        // ---- phase4: gi partials — 3 LDS rows + 12 reg rows + 29 streamed (ascending i) ----
        if (tid < 678) {
            float a0 = 0.f, a1 = 0.f, a2 = 0.f, a3 = 0.f;
#pragma unroll
            for (int i = 0; i < 3; ++i) {
                h8f w = *(const h8f*)(wihl + (size_t)(p4_ks * 3 + i) * 452 + 4 * p4_mq);
                h2f cp = c_p[p4_ks * 44 + i];
                a0 = __builtin_amdgcn_fdot2(h2f{w[0], w[1]}, cp, a0, false);
                a1 = __builtin_amdgcn_fdot2(h2f{w[2], w[3]}, cp, a1, false);
                a2 = __builtin_amdgcn_fdot2(h2f{w[4], w[5]}, cp, a2, false);
                a3 = __builtin_amdgcn_fdot2(h2f{w[6], w[7]}, cp, a3, false);
            }
#pragma unroll
            for (int i = 3; i < 15; ++i) {
                h8f w = wihr[i - 3];
                h2f cp = c_p[p4_ks * 44 + i];
                a0 = __builtin_amdgcn_fdot2(h2f{w[0], w[1]}, cp, a0, false);
                a1 = __builtin_amdgcn_fdot2(h2f{w[2], w[3]}, cp, a1, false);
                a2 = __builtin_amdgcn_fdot2(h2f{w[4], w[5]}, cp, a2, false);
                a3 = __builtin_amdgcn_fdot2(h2f{w[6], w[7]}, cp, a3, false);
            }
#pragma unroll 15
            for (int i = 15; i < 44; ++i) {
                int row = p4_ks * 44 + i;
                if (row < 256) {
                    h8f w = *(const h8f*)(wih_base + (size_t)i * 452);
                    h2f cp = c_p[row];
                    a0 = __builtin_amdgcn_fdot2(h2f{w[0], w[1]}, cp, a0, false);
                    a1 = __builtin_amdgcn_fdot2(h2f{w[2], w[3]}, cp, a1, false);
                    a2 = __builtin_amdgcn_fdot2(h2f{w[4], w[5]}, cp, a2, false);
                    a3 = __builtin_amdgcn_fdot2(h2f{w[6], w[7]}, cp, a3, false);
                }
            }
            *(float4*)(red + p4_ks * 456 + 4 * p4_mq) = float4{a0, a1, a2, a3};
        }
        __syncthreads();
        // ---- GRU: gif 6-way reduce inline + combine + state update + output ----
        if (tid < 150) {
            float gi0 = red[tid] + red[456 + tid] + red[912 + tid] + red[1368 + tid] + red[1824 + tid] + red[2280 + tid];
            int m1 = 150 + tid;
            float gi1 = red[m1] + red[456 + m1] + red[912 + m1] + red[1368 + m1] + red[1824 + m1] + red[2280 + m1];
            int m2 = 300 + tid;
            float gi2 = red[m2] + red[456 + m2] + red[912 + m2] + red[1368 + m2] + red[1824 + m2] + red[2280 + m2];
            float r = sigm(gi0 + bihL[tid] + ghf[tid]);
            float z = sigm(gi1 + bihL[150 + tid] + ghf[150 + tid]);
            float n = tanh_f(gi2 + bihL[300 + tid] + r * ghf[300 + tid]);
            float vn = (1.f - z) * n + z * vf[tid];
            vf[tid] = vn;
            vh[tid] = (_Float16)vn;
            out[(size_t)t * 9600 + b * 150 + tid] = vn;
        }
        __syncthreads();
    }
}

// ---------------- launch ----------------
extern "C" void kernel_launch(void* const* d_in, const int* in_sizes, int n_in,
                              void* d_out, int out_size, void* d_ws, size_t ws_size,
                              hipStream_t stream) {
    const float* Up  = (const float*)d_in[0];
    const float* Uq  = (const float*)d_in[1];
    const float* Wp  = (const float*)d_in[2];
    const float* Wq  = (const float*)d_in[3];
    const float* Wv  = (const float*)d_in[4];
    const float* Wg  = (const float*)d_in[5];
    const float* V   = (const float*)d_in[6];
    const float* v0  = (const float*)d_in[7];
    const float* Wih = (const float*)d_in[8];
    const float* Whh = (const float*)d_in[9];
    const float* bih = (const float*)d_in[10];
    const float* bhh = (const float*)d_in[11];
    float* out = (float*)d_out;
    float* ws = (float*)d_ws;

    if (ws_size < WS_FLOATS * sizeof(float)) return;

    k_prep<<<1701, 256, 0, stream>>>(Wp, Wq, Wg, Wv, Whh, Wih, ws);
    k_tr<<<500, 256, 0, stream>>>(Up, ws + OFF_UPT);
    k_tr<<<64, 256, 0, stream>>>(Uq, ws + OFF_UQT);
    // Gu[t][b][j] = Up[t] @ Wg1^T (f16) — before P1 GEMM (WG1 aliases P1)
    k_gemm<<<8000, 256, 0, stream>>>(ws + OFF_UPT, ws + OFF_WG1, nullptr, (_Float16*)(ws + OFF_GUH), 512, 16);
    // P1[t][b][h] = Up[t] @ Wpf^T (f32)
    k_gemm<<<2500, 256, 0, stream>>>(ws + OFF_UPT, ws + OFF_WPF, ws + OFF_P1, nullptr, 150, 5);
    // Wuq[q][b][h] = Uq[q] @ Wqf^T (f32) — consumes UQT before k_uqt overwrites
    k_gemm<<<320, 256, 0, stream>>>(ws + OFF_UQT, ws + OFF_WQF, ws + OFF_WUQ, nullptr, 150, 5);
    // UqT2[b][q2][d] f16 pairs — aliases UQT (safe after Wuq GEMM)
    k_uqt<<<64, 256, 0, stream>>>(Uq, (h2f*)(ws + OFF_UQT2));
    // M2[b][q2][j] = f16(Uq_b) @ Wgf2 — aliases UPT (dead after the GEMMs above)
    k_mgemm<<<64, 512, 0, stream>>>(Uq, ws, (h2f*)(ws + OFF_M2));
    // scan v17: pb-only phase1 + gh-GEMV concurrent with phase2a (wave-level overlap)
    k_scan17<<<64, 768, 0, stream>>>(V, v0, bih, bhh, ws, out);
}

// Round 19
// 5603.111 us; speedup vs baseline: 1.1645x; 1.1645x over previous
//
#include <hip/hip_runtime.h>
#include <hip/hip_fp16.h>

// LP=500, LQ=64, B=64, D=256, H=150
#define LP 500

typedef _Float16 h2f __attribute__((ext_vector_type(2)));
typedef _Float16 h8f __attribute__((ext_vector_type(8)));

// ---------------- workspace layout (float slots) ----------------
constexpr size_t OFF_WVH2 = 0;         // [76][608] h2f: cols 0..149 Wv rows, 150..599 Whh rows, pads 0
constexpr size_t OFF_WGF2 = 46208;     // [128][512] h2f folded Wg cc-part
constexpr size_t OFF_WIH2 = 111744;    // [256][452] h2f Wih (cols 450,451 zero)
constexpr size_t OFF_WPF  = 227456;    // [150][256] f32 folded Wp
constexpr size_t OFF_WQF  = 265856;    // [150][256] f32 folded Wq
constexpr size_t OFF_WUQ  = 304256;    // [64][64][150] f32 Wuq[q][b][h]
constexpr size_t OFF_P1   = 918656;    // [500][64][150] f32  (WG1 [512][256] f32 ALIASED here pre-P1)
constexpr size_t OFF_WG1  = OFF_P1;    // alias: consumed by Gu GEMM before P1 GEMM overwrites
constexpr size_t OFF_GUH  = 5718656;   // [500][64][512] f16 Gu
constexpr size_t OFF_UPT  = 13910656;  // [500][256][64] f32 (M2 [64][32][512] h2f ALIASED post-GEMMs)
constexpr size_t OFF_M2   = OFF_UPT;   // alias: UPT dead after the three k_gemm calls
constexpr size_t OFF_UQT  = 22102656;  // [64][256][64] f32   (UqT2 [64][32][256] h2f ALIASED post-GEMM)
constexpr size_t OFF_UQT2 = OFF_UQT;
constexpr size_t WS_FLOATS = 23151232; // 92.6 MB

// ---------------- helpers ----------------
__device__ __forceinline__ float fast_rcp(float x) { return __builtin_amdgcn_rcpf(x); }
__device__ __forceinline__ float sigm(float x)   { return fast_rcp(1.f + __expf(-x)); }
__device__ __forceinline__ float tanh_f(float x) { return 1.f - 2.f * fast_rcp(1.f + __expf(2.f * x)); }

// ---------------- precompute: weight folds + f16 column-major packs ----------------
__global__ __launch_bounds__(256) void k_prep(const float* __restrict__ Wp, const float* __restrict__ Wq,
                                              const float* __restrict__ Wg, const float* __restrict__ Wv,
                                              const float* __restrict__ Whh, const float* __restrict__ Wih,
                                              float* __restrict__ ws) {
    int i = blockIdx.x * 256 + threadIdx.x;
    if (i < 46208) {  // WVH2 [76][608]
        int k2 = i / 608, m = i - k2 * 608;
        float lo = 0.f, hi = 0.f;
        if (k2 < 75 && m < 600) {
            if (m < 150) { lo = Wv[m * 150 + 2 * k2]; hi = Wv[m * 150 + 2 * k2 + 1]; }
            else { int mm = m - 150; lo = Whh[mm * 150 + 2 * k2]; hi = Whh[mm * 150 + 2 * k2 + 1]; }
        }
        ((h2f*)(ws + OFF_WVH2))[i] = h2f{(_Float16)lo, (_Float16)hi};
        return;
    }
    i -= 46208;
    if (i < 65536) {  // WGF2 [128][512]
        int k2 = i >> 9, j = i & 511;
        int d = 2 * k2;
        size_t r = (size_t)(512 + j) * 1024;
        float lo = Wg[r + 512 + d] + Wg[r + 768 + d];
        float hi = Wg[r + 512 + d + 1] + Wg[r + 768 + d + 1];
        ((h2f*)(ws + OFF_WGF2))[i] = h2f{(_Float16)lo, (_Float16)hi};
        return;
    }
    i -= 65536;
    if (i < 115712) {  // WIH2 [256][452]
        int k2 = i / 452, m = i - k2 * 452;
        float lo = 0.f, hi = 0.f;
        if (m < 450) { lo = Wih[m * 512 + 2 * k2]; hi = Wih[m * 512 + 2 * k2 + 1]; }
        ((h2f*)(ws + OFF_WIH2))[i] = h2f{(_Float16)lo, (_Float16)hi};
        return;
    }
    i -= 115712;
    if (i < 38400) { int h = i >> 8, d = i & 255; ws[OFF_WPF + i] = Wp[h * 512 + d] + Wp[h * 512 + 256 + d]; return; }
    i -= 38400;
    if (i < 38400) { int h = i >> 8, d = i & 255; ws[OFF_WQF + i] = Wq[h * 512 + d] + Wq[h * 512 + 256 + d]; return; }
    i -= 38400;
    if (i < 131072) { int j = i >> 8, d = i & 255; size_t r = (size_t)(512 + j) * 1024; ws[OFF_WG1 + i] = Wg[r + d] + Wg[r + 256 + d]; return; }
}

// transpose X[t][64][256] -> XT[t][256][64], one block per t
__global__ __launch_bounds__(256) void k_tr(const float* __restrict__ X, float* __restrict__ XT) {
    __shared__ float tile[64][65];
    size_t base = (size_t)blockIdx.x * 16384;
    for (int ph = 0; ph < 4; ++ph) {
        for (int i = threadIdx.x; i < 4096; i += 256) {
            int b = i >> 6, dl = i & 63;
            tile[b][dl] = X[base + (size_t)b * 256 + ph * 64 + dl];
        }
        __syncthreads();
        for (int i = threadIdx.x; i < 4096; i += 256) {
            int d = i >> 6, bl = i & 63;
            XT[base + (size_t)(ph * 64 + d) * 64 + bl] = tile[bl][d];
        }
        __syncthreads();
    }
}

// acc[h,b] = sum_d XT[t,d,b]*Wf[h,d]; writes out[t][b][Hrows] as f32 or f16
__global__ __launch_bounds__(256) void k_gemm(const float* __restrict__ XT, const float* __restrict__ Wf,
                                              float* __restrict__ outF, _Float16* __restrict__ outH,
                                              int Hrows, int tilesPerT) {
    __shared__ float OL[64 * 33];
    int bidx = blockIdx.x;
    int t = bidx / tilesPerT, tile = bidx - t * tilesPerT;
    int w = threadIdx.x >> 6, lane = threadIdx.x & 63;
    int h0 = __builtin_amdgcn_readfirstlane(tile * 32 + w * 8);
    const float* x = XT + (size_t)t * 16384;
    float acc[8];
    const float* wr[8];
#pragma unroll
    for (int r = 0; r < 8; ++r) {
        int hr = h0 + r; if (hr >= Hrows) hr = Hrows - 1;
        wr[r] = Wf + (size_t)hr * 256;
        acc[r] = 0.f;
    }
    for (int d = 0; d < 256; d += 4) {
        float cv0 = x[(d + 0) * 64 + lane];
        float cv1 = x[(d + 1) * 64 + lane];
        float cv2 = x[(d + 2) * 64 + lane];
        float cv3 = x[(d + 3) * 64 + lane];
#pragma unroll
        for (int r = 0; r < 8; ++r) {
            float4 wv = *(const float4*)(wr[r] + d);
            acc[r] += cv0 * wv.x + cv1 * wv.y + cv2 * wv.z + cv3 * wv.w;
        }
    }
#pragma unroll
    for (int r = 0; r < 8; ++r) { int hl = w * 8 + r; OL[lane * 33 + hl] = acc[r]; }
    __syncthreads();
    int hbase = tile * 32;
    int nh = Hrows - hbase; if (nh > 32) nh = 32;
    for (int i = threadIdx.x; i < 64 * nh; i += 256) {
        int b = i / nh, hl = i - b * nh;
        float val = OL[b * 33 + hl];
        size_t idx = (size_t)t * 64 * Hrows + (size_t)b * Hrows + hbase + hl;
        if (outF) outF[idx] = val;
        else outH[idx] = (_Float16)val;
    }
}

// UqT2[b][q2][d] = (f16 Uq[2q2][b][d], f16 Uq[2q2+1][b][d])
__global__ __launch_bounds__(256) void k_uqt(const float* __restrict__ Uq, h2f* __restrict__ UqT2) {
    int b = blockIdx.x, d = threadIdx.x;
    for (int q2 = 0; q2 < 32; ++q2) {
        float lo = Uq[(size_t)(2 * q2) * 16384 + b * 256 + d];
        float hi = Uq[(size_t)(2 * q2 + 1) * 16384 + b * 256 + d];
        UqT2[(size_t)b * 8192 + q2 * 256 + d] = h2f{(_Float16)lo, (_Float16)hi};
    }
}

// M[b][q][j] = sum_d f16(Uq[q][b][d]) * Wgf2[d][j]; stored as q-pairs M2[b][q2][j] h2f.
// NOTE: no __restrict__ on ws_ro/M2 (both derive from ws — avoid aliasing-UB risk).
__global__ __launch_bounds__(512) void k_mgemm(const float* __restrict__ Uq,
                                               const float* ws_ro,
                                               h2f* M2) {
    __shared__ _Float16 uqf[64 * 256];  // 32KB, f16-rounded Uq rows (matches uql quantization)
    int b = blockIdx.x, j = threadIdx.x;
    const h2f* Wgf2 = (const h2f*)(ws_ro + OFF_WGF2);
    for (int u = threadIdx.x; u < 16384; u += 512) {
        int q = u >> 8, d = u & 255;
        uqf[u] = (_Float16)Uq[(size_t)q * 16384 + b * 256 + d];
    }
    __syncthreads();
    for (int qc = 0; qc < 8; ++qc) {
        float acc[8];
#pragma unroll
        for (int i = 0; i < 8; ++i) acc[i] = 0.f;
        for (int k2 = 0; k2 < 128; ++k2) {
            h2f w = Wgf2[k2 * 512 + j];
            float wlo = (float)w[0], whi = (float)w[1];
#pragma unroll
            for (int i = 0; i < 8; ++i) {
                acc[i] += (float)uqf[(qc * 8 + i) * 256 + 2 * k2] * wlo
                        + (float)uqf[(qc * 8 + i) * 256 + 2 * k2 + 1] * whi;
            }
        }
#pragma unroll
        for (int p = 0; p < 4; ++p)
            M2[(size_t)b * 16384 + (size_t)(qc * 4 + p) * 512 + j] =
                h2f{(_Float16)acc[2 * p], (_Float16)acc[2 * p + 1]};
    }
}

// ---------------- per-batch persistent scan: 64 blocks x 768 threads ----------------
// v16 FINAL (revert of regressed v17 per R18 post-mortem: keeping GEMV phases maximally
// wide beats wave-specialized overlap — serial-depth-bound, not BW-bound).
// Structure: v13 skeleton + M-path (g = M^T a, K=64, concurrent with cc = Uq^T a) +
// fusions B (gh-reduce during softmax) and C (gif reduce inline in GRU). 8 barriers.
// Hosting at its measured fixed point: LDS 152.5KB (uql+m2l+wihl), regs 84 VGPR +
// 48 AGPR (wihr) — any additional hosted array spills (R15/R16).
// Verified: scan 5095 µs, total 5604 µs, absmax 0.015625, WRITE_SIZE 19500 KB.
__global__ __launch_bounds__(768, 3) void k_scan16(
    const float* __restrict__ V, const float* __restrict__ v0,
    const float* __restrict__ bih, const float* __restrict__ bhh,
    const float* __restrict__ ws, float* __restrict__ out) {
    __shared__ __attribute__((aligned(16))) float red[3072];
    __shared__ __attribute__((aligned(16))) _Float16 vh[152];
    __shared__ float pbf[152];
    __shared__ float ghf[452];
    __shared__ float Vb[152];
    __shared__ float bihL[452];
    __shared__ float bhhL[452];
    __shared__ float vf[152];
    __shared__ float sa[64];
    __shared__ __attribute__((aligned(8))) h2f sah[32];
    __shared__ __attribute__((aligned(8))) h2f c_p[256];
    __shared__ __attribute__((aligned(16))) h2f uql[8192];      // 32KB Uq f16 q-pairs
    __shared__ __attribute__((aligned(16))) h2f m2l[16384];     // 64KB M q-pairs
    __shared__ __attribute__((aligned(16))) h2f wihl[18 * 452]; // 32.5KB Wih2 rows ks*44+i, i<3

    const int tid = threadIdx.x, b = blockIdx.x;
    const int lane = tid & 63;
    const h2f* Wvh2 = (const h2f*)(ws + OFF_WVH2);
    const h2f* Wih2 = (const h2f*)(ws + OFF_WIH2);
    const h2f* UqT2b = (const h2f*)(ws + OFF_UQT2) + (size_t)b * 8192;
    const h2f* M2b = (const h2f*)(ws + OFF_M2) + (size_t)b * 16384;
    const float* WuqG = ws + OFF_WUQ;
    const float* P1 = ws + OFF_P1;
    const _Float16* GuH = (const _Float16*)(ws + OFF_GUH);

    // phase1: M=608(600 live), 152 quads x ks=5 (760 threads), 15 k2 each
    const int p1_ks = tid / 152, p1_mq = tid - p1_ks * 152;
    const h2f* wv_base = Wvh2 + (size_t)(p1_ks * 15) * 608 + 4 * p1_mq;
    // phase4: M=452(450 live), 113 quads x ks=6 (678 threads), 44 rows each
    const int p4_ks = tid / 113, p4_mq = tid - p4_ks * 113;
    const h2f* wih_base = Wih2 + (size_t)(p4_ks * 44) * 452 + 4 * p4_mq;

    // phase2a setup: wave w12 handles nq q's (6 for w<4, 5 for w>=4); Wuq in regs
    const int w12 = tid >> 6;
    const int nq = (w12 < 4) ? 6 : 5;
    const int q0 = (w12 < 4) ? w12 * 6 : 24 + (w12 - 4) * 5;
    _Float16 wq[18];
#pragma unroll
    for (int i = 0; i < 6; ++i)
#pragma unroll
        for (int it = 0; it < 3; ++it) {
            int idx = lane + 64 * it;
            wq[i * 3 + it] = (_Float16)((i < nq && idx < 150) ? WuqG[(size_t)(q0 + i) * 9600 + b * 150 + idx] : 0.f);
        }

    // register-resident Wih2 rows i=3..14 of each 44-row group (48 regs, AGPR-hosted)
    h8f wihr[12];
#pragma unroll
    for (int i = 0; i < 12; ++i)
        wihr[i] = (tid < 678) ? *(const h8f*)(wih_base + (size_t)(3 + i) * 452) : h8f{};

    // one-time LDS residency fills (h8f vector copies)
    {
        const h8f* su = (const h8f*)UqT2b;
        h8f* du = (h8f*)uql;
        for (int u = tid; u < 2048; u += 768) du[u] = su[u];
        const h8f* sm = (const h8f*)M2b;
        h8f* dm = (h8f*)m2l;
        for (int u = tid; u < 4096; u += 768) dm[u] = sm[u];
        h8f* dw = (h8f*)wihl;
        for (int u = tid; u < 2034; u += 768) {       // 18 rows x 113 h8f
            int slot = u / 113, off = u - slot * 113; // slot = ks*3+i
            int ks = slot / 3, i = slot - ks * 3;
            dw[u] = *(const h8f*)(Wih2 + (size_t)(ks * 44 + i) * 452 + off * 4);
        }
    }

    // one-time per-b LDS init
    for (int i = tid; i < 150; i += 768) { Vb[i] = V[b * 150 + i]; float v = v0[b * 150 + i]; vf[i] = v; vh[i] = (_Float16)v; }
    for (int i = tid; i < 450; i += 768) { bihL[i] = bih[i]; bhhL[i] = bhh[i]; }
    if (tid < 2) vh[150 + tid] = (_Float16)0.f;
    __syncthreads();

    for (int t = 0; t < LP; ++t) {
        // ---- prefetch this step's HBM/L2-resident per-step data ----
        float p1v = 0.f;
        if (tid < 150) p1v = P1[(size_t)t * 9600 + b * 150 + tid];
        float guv = 0.f;
        if (tid < 512) guv = (float)GuH[(size_t)t * 32768 + b * 512 + tid];

        // ---- phase1: [pb|gh](m) partials = sum_k Wvh[k][m]*v[k], 5 k-groups x 15 ----
        if (tid < 760) {
            const h2f* vh2 = (const h2f*)vh;
            float a0 = 0.f, a1 = 0.f, a2 = 0.f, a3 = 0.f;
#pragma unroll 5
            for (int i = 0; i < 15; ++i) {
                h8f w = *(const h8f*)(wv_base + (size_t)i * 608);
                h2f x = vh2[p1_ks * 15 + i];
                a0 = __builtin_amdgcn_fdot2(h2f{w[0], w[1]}, x, a0, false);
                a1 = __builtin_amdgcn_fdot2(h2f{w[2], w[3]}, x, a1, false);
                a2 = __builtin_amdgcn_fdot2(h2f{w[4], w[5]}, x, a2, false);
                a3 = __builtin_amdgcn_fdot2(h2f{w[6], w[7]}, x, a3, false);
            }
            *(float4*)(red + p1_ks * 608 + 4 * p1_mq) = float4{a0, a1, a2, a3};
        }
        __syncthreads();
        if (tid < 150) {  // pbf-reduce only (fusion B moved gh to the softmax phase)
            float s = red[tid] + red[608 + tid] + red[1216 + tid] + red[1824 + tid] + red[2432 + tid];
            pbf[tid] = s + p1v;
        }
        __syncthreads();
        // ---- phase2a: s[q] = sum_h tanh(pb+wuq)*V, 12 waves x 5-6 q ----
        {
#pragma unroll
            for (int i = 0; i < 6; ++i) {
                if (i < nq) {
                    float part = 0.f;
#pragma unroll
                    for (int it = 0; it < 3; ++it) {
                        int idx = lane + 64 * it;
                        if (idx < 150)
                            part += tanh_f(pbf[idx] + (float)wq[i * 3 + it]) * Vb[idx];
                    }
                    part += __shfl_xor(part, 32); part += __shfl_xor(part, 16);
                    part += __shfl_xor(part, 8);  part += __shfl_xor(part, 4);
                    part += __shfl_xor(part, 2);  part += __shfl_xor(part, 1);
                    if (lane == 0) sa[q0 + i] = part;
                }
            }
        }
        __syncthreads();
        // ---- softmax (wave0) ∥ gh-reduce (threads 64..513; red still live) ----
        if (tid < 64) {
            float s = sa[tid];
            float m = s;
            m = fmaxf(m, __shfl_xor(m, 32)); m = fmaxf(m, __shfl_xor(m, 16));
            m = fmaxf(m, __shfl_xor(m, 8));  m = fmaxf(m, __shfl_xor(m, 4));
            m = fmaxf(m, __shfl_xor(m, 2));  m = fmaxf(m, __shfl_xor(m, 1));
            float e = __expf(s - m);
            float su = e;
            su += __shfl_xor(su, 32); su += __shfl_xor(su, 16); su += __shfl_xor(su, 8);
            su += __shfl_xor(su, 4);  su += __shfl_xor(su, 2);  su += __shfl_xor(su, 1);
            float a = e * fast_rcp(su);
            float an = __shfl_xor(a, 1);
            if ((tid & 1) == 0) sah[tid >> 1] = h2f{(_Float16)a, (_Float16)an};
        } else if (tid < 514) {
            int m = 86 + tid;  // tid 64..513 -> m 150..599
            ghf[m - 150] = red[m] + red[608 + m] + red[1216 + m] + red[1824 + m] + red[2432 + m] + bhhL[m - 150];
        }
        __syncthreads();
        // ---- phase2b': cc partials (256 thr) ∥ g partials from M (512 thr) ----
        if (tid < 256) {
            int cks = tid >> 6, cqd = tid & 63;
            float a0 = 0.f, a1 = 0.f, a2 = 0.f, a3 = 0.f;
#pragma unroll
            for (int i = 0; i < 8; ++i) {
                int q2 = cks * 8 + i;
                h8f u = *(const h8f*)(uql + q2 * 256 + 4 * cqd);
                h2f ap = sah[q2];
                a0 = __builtin_amdgcn_fdot2(h2f{u[0], u[1]}, ap, a0, false);
                a1 = __builtin_amdgcn_fdot2(h2f{u[2], u[3]}, ap, a1, false);
                a2 = __builtin_amdgcn_fdot2(h2f{u[4], u[5]}, ap, a2, false);
                a3 = __builtin_amdgcn_fdot2(h2f{u[6], u[7]}, ap, a3, false);
            }
            *(float4*)(red + cks * 256 + 4 * cqd) = float4{a0, a1, a2, a3};
        } else {
            int gt = tid - 256, gks = gt >> 7, gjq = gt & 127;
            float a0 = 0.f, a1 = 0.f, a2 = 0.f, a3 = 0.f;
#pragma unroll
            for (int i = 0; i < 8; ++i) {
                int q2 = gks * 8 + i;
                h8f m8 = *(const h8f*)(m2l + q2 * 512 + 4 * gjq);
                h2f ap = sah[q2];
                a0 = __builtin_amdgcn_fdot2(h2f{m8[0], m8[1]}, ap, a0, false);
                a1 = __builtin_amdgcn_fdot2(h2f{m8[2], m8[3]}, ap, a1, false);
                a2 = __builtin_amdgcn_fdot2(h2f{m8[4], m8[5]}, ap, a2, false);
                a3 = __builtin_amdgcn_fdot2(h2f{m8[6], m8[7]}, ap, a3, false);
            }
            *(float4*)(red + 1024 + gks * 512 + 4 * gjq) = float4{a0, a1, a2, a3};
        }
        __syncthreads();
        // ---- grc: g reduce + cc reduce + c_ pack (512 threads, j = tid) ----
        if (tid < 512) {
            float g = guv + red[1024 + tid] + red[1536 + tid] + red[2048 + tid] + red[2560 + tid];
            int dd = tid & 255;
            float cc = red[dd] + red[256 + dd] + red[512 + dd] + red[768 + dd];
            float val = sigm(g) * cc;
            float vn2 = __shfl_xor(val, 1);
            if ((tid & 1) == 0) c_p[tid >> 1] = h2f{(_Float16)val, (_Float16)vn2};
        }
        __syncthreads();
        // ---- phase4: gi partials — 3 LDS rows + 12 reg rows + 29 streamed (ascending i) ----
        if (tid < 678) {
            float a0 = 0.f, a1 = 0.f, a2 = 0.f, a3 = 0.f;
#pragma unroll
            for (int i = 0; i < 3; ++i) {
                h8f w = *(const h8f*)(wihl + (size_t)(p4_ks * 3 + i) * 452 + 4 * p4_mq);
                h2f cp = c_p[p4_ks * 44 + i];
                a0 = __builtin_amdgcn_fdot2(h2f{w[0], w[1]}, cp, a0, false);
                a1 = __builtin_amdgcn_fdot2(h2f{w[2], w[3]}, cp, a1, false);
                a2 = __builtin_amdgcn_fdot2(h2f{w[4], w[5]}, cp, a2, false);
                a3 = __builtin_amdgcn_fdot2(h2f{w[6], w[7]}, cp, a3, false);
            }
#pragma unroll
            for (int i = 3; i < 15; ++i) {
                h8f w = wihr[i - 3];
                h2f cp = c_p[p4_ks * 44 + i];
                a0 = __builtin_amdgcn_fdot2(h2f{w[0], w[1]}, cp, a0, false);
                a1 = __builtin_amdgcn_fdot2(h2f{w[2], w[3]}, cp, a1, false);
                a2 = __builtin_amdgcn_fdot2(h2f{w[4], w[5]}, cp, a2, false);
                a3 = __builtin_amdgcn_fdot2(h2f{w[6], w[7]}, cp, a3, false);
            }
#pragma unroll 15
            for (int i = 15; i < 44; ++i) {
                int row = p4_ks * 44 + i;
                if (row < 256) {
                    h8f w = *(const h8f*)(wih_base + (size_t)i * 452);
                    h2f cp = c_p[row];
                    a0 = __builtin_amdgcn_fdot2(h2f{w[0], w[1]}, cp, a0, false);
                    a1 = __builtin_amdgcn_fdot2(h2f{w[2], w[3]}, cp, a1, false);
                    a2 = __builtin_amdgcn_fdot2(h2f{w[4], w[5]}, cp, a2, false);
                    a3 = __builtin_amdgcn_fdot2(h2f{w[6], w[7]}, cp, a3, false);
                }
            }
            *(float4*)(red + p4_ks * 456 + 4 * p4_mq) = float4{a0, a1, a2, a3};
        }
        __syncthreads();
        // ---- GRU: fusion C — gif 6-way reduce inline (same addend order) ----
        if (tid < 150) {
            float gi0 = red[tid] + red[456 + tid] + red[912 + tid] + red[1368 + tid] + red[1824 + tid] + red[2280 + tid];
            int m1 = 150 + tid;
            float gi1 = red[m1] + red[456 + m1] + red[912 + m1] + red[1368 + m1] + red[1824 + m1] + red[2280 + m1];
            int m2 = 300 + tid;
            float gi2 = red[m2] + red[456 + m2] + red[912 + m2] + red[1368 + m2] + red[1824 + m2] + red[2280 + m2];
            float r = sigm(gi0 + bihL[tid] + ghf[tid]);
            float z = sigm(gi1 + bihL[150 + tid] + ghf[150 + tid]);
            float n = tanh_f(gi2 + bihL[300 + tid] + r * ghf[300 + tid]);
            float vn = (1.f - z) * n + z * vf[tid];
            vf[tid] = vn;
            vh[tid] = (_Float16)vn;
            out[(size_t)t * 9600 + b * 150 + tid] = vn;
        }
        __syncthreads();
    }
}

// ---------------- launch ----------------
extern "C" void kernel_launch(void* const* d_in, const int* in_sizes, int n_in,
                              void* d_out, int out_size, void* d_ws, size_t ws_size,
                              hipStream_t stream) {
    const float* Up  = (const float*)d_in[0];
    const float* Uq  = (const float*)d_in[1];
    const float* Wp  = (const float*)d_in[2];
    const float* Wq  = (const float*)d_in[3];
    const float* Wv  = (const float*)d_in[4];
    const float* Wg  = (const float*)d_in[5];
    const float* V   = (const float*)d_in[6];
    const float* v0  = (const float*)d_in[7];
    const float* Wih = (const float*)d_in[8];
    const float* Whh = (const float*)d_in[9];
    const float* bih = (const float*)d_in[10];
    const float* bhh = (const float*)d_in[11];
    float* out = (float*)d_out;
    float* ws = (float*)d_ws;

    if (ws_size < WS_FLOATS * sizeof(float)) return;

    k_prep<<<1701, 256, 0, stream>>>(Wp, Wq, Wg, Wv, Whh, Wih, ws);
    k_tr<<<500, 256, 0, stream>>>(Up, ws + OFF_UPT);
    k_tr<<<64, 256, 0, stream>>>(Uq, ws + OFF_UQT);
    // Gu[t][b][j] = Up[t] @ Wg1^T (f16) — before P1 GEMM (WG1 aliases P1)
    k_gemm<<<8000, 256, 0, stream>>>(ws + OFF_UPT, ws + OFF_WG1, nullptr, (_Float16*)(ws + OFF_GUH), 512, 16);
    // P1[t][b][h] = Up[t] @ Wpf^T (f32)
    k_gemm<<<2500, 256, 0, stream>>>(ws + OFF_UPT, ws + OFF_WPF, ws + OFF_P1, nullptr, 150, 5);
    // Wuq[q][b][h] = Uq[q] @ Wqf^T (f32) — consumes UQT before k_uqt overwrites
    k_gemm<<<320, 256, 0, stream>>>(ws + OFF_UQT, ws + OFF_WQF, ws + OFF_WUQ, nullptr, 150, 5);
    // UqT2[b][q2][d] f16 pairs — aliases UQT (safe after Wuq GEMM)
    k_uqt<<<64, 256, 0, stream>>>(Uq, (h2f*)(ws + OFF_UQT2));
    // M2[b][q2][j] = f16(Uq_b) @ Wgf2 — aliases UPT (dead after the GEMMs above)
    k_mgemm<<<64, 512, 0, stream>>>(Uq, ws, (h2f*)(ws + OFF_M2));
    // scan v16 FINAL: M-path + fusions B/C, 8 barriers (verified best: 5604 µs total)
    k_scan16<<<64, 768, 0, stream>>>(V, v0, bih, bhh, ws, out);
}